// Round 9
// baseline (202.388 us; speedup 1.0000x reference)
//
#include <hip/hip_runtime.h>
#include <stdint.h>

// LSTM cell: B=8192, DIN=1024, DOUT=1024, fp32 in/out.
// R9: 256x256 tile, BK=32, FOUR-deep LDS ring -> staging fully decoupled
// from compute (stage(s) targets buf[(s+3)&3], last read at step s-2).
// Per step: {stage 4 glds -> buf[s+3]; 12 ds_read_b128 <- buf[s]; LG0;
//            32 MFMA (setprio); VMC(8); BAR}.
// vmcnt(8) completes stage(s-2) = step s+1's buffer (flight 2-3 steps).
// Tails: s=61 VMC(4), s=62 VMC(0), s=63 none.
// BK=32 swizzle: 64B rows, 4 slots/row; phys_slot = slot ^ ((row>>1)&3).
//   read: roff = ((l4 ^ ((l15>>1)&3))<<3)  -> 8 dwords/bank (conflict-free)
//   stage: src k-offset = ((t&3)^((t>>3)&3))*8 (matching involution).
// XCD map: jt = xcd*2 + (idx&1) -> per-XCD B panels 2MB (L2-resident).

typedef __attribute__((ext_vector_type(8))) _Float16 half8;
typedef __attribute__((ext_vector_type(4))) _Float16 half4;
typedef __attribute__((ext_vector_type(4))) float f32x4;

__device__ __forceinline__ void gload_lds16(const void* g, void* l) {
  __builtin_amdgcn_global_load_lds(
      (const __attribute__((address_space(1))) void*)g,
      (__attribute__((address_space(3))) void*)l, 16, 0, 0);
}

__device__ __forceinline__ float sigf(float x) { return 1.0f / (1.0f + __expf(-x)); }
__device__ __forceinline__ float tanhf_(float x) { return 1.0f - 2.0f / (__expf(2.0f * x) + 1.0f); }

#define FENCE asm volatile("" ::: "memory")
#define BAR do { FENCE; __builtin_amdgcn_s_barrier(); FENCE; } while (0)
#define LG0 do { asm volatile("s_waitcnt lgkmcnt(0)" ::: "memory"); \
                 __builtin_amdgcn_sched_barrier(0); } while (0)
#define VMC(n) asm volatile("s_waitcnt vmcnt(" #n ")" ::: "memory")

// ---------------- packing kernels ----------------

// Wt[n'][k], n' = (j>>4)*64 + g*16 + (j&15); k<1024 -> Wx_g[k][j], else Wh_g.
__global__ void lstm_pack_w8(const float* __restrict__ Wxi, const float* __restrict__ Whi,
                             const float* __restrict__ Wxf, const float* __restrict__ Whf,
                             const float* __restrict__ Wxg, const float* __restrict__ Whg,
                             const float* __restrict__ Wxo, const float* __restrict__ Who,
                             _Float16* __restrict__ Wt) {
  __shared__ float tile[32][33];
  int nt = blockIdx.x;          // 0..127 : g = nt&3, jt32 = nt>>2
  int kt = blockIdx.y;          // 0..63
  int g = nt & 3, jt32 = nt >> 2;
  const float* Wx[4] = {Wxi, Wxf, Wxg, Wxo};
  const float* Wh[4] = {Whi, Whf, Whg, Who};
  int k0 = kt * 32;
  const float* src = (k0 < 1024) ? (Wx[g] + (size_t)k0 * 1024)
                                 : (Wh[g] + (size_t)(k0 - 1024) * 1024);
  int j0 = jt32 * 32;
  int t = threadIdx.x;
  int cc = t & 31, r0 = t >> 5;
  #pragma unroll
  for (int p = 0; p < 4; ++p) {
    int r = p * 8 + r0;
    tile[r][cc] = src[(size_t)r * 1024 + j0 + cc];
  }
  __syncthreads();
  int jj = t >> 3, kk = (t & 7) * 4;
  int j = j0 + jj;
  int np = ((j >> 4) << 6) + g * 16 + (j & 15);
  half4 v;
  v[0] = (_Float16)tile[kk + 0][jj];
  v[1] = (_Float16)tile[kk + 1][jj];
  v[2] = (_Float16)tile[kk + 2][jj];
  v[3] = (_Float16)tile[kk + 3][jj];
  *(half4*)(Wt + (size_t)np * 2048 + k0 + kk) = v;
}

// Xh[8192][2048] fp16: k<1024 -> x[row][k] else h[row][k-1024]
__global__ void lstm_pack_xh(const float* __restrict__ x, const float* __restrict__ h,
                             _Float16* __restrict__ Xh) {
  size_t t = (size_t)blockIdx.x * 256 + threadIdx.x;
  size_t e = t * 8;
  int row = (int)(e >> 11), k = (int)(e & 2047);
  const float* src = (k < 1024) ? (x + (size_t)row * 1024 + k)
                                : (h + (size_t)row * 1024 + (k - 1024));
  float4 f0 = *(const float4*)src;
  float4 f1 = *(const float4*)(src + 4);
  half8 v;
  v[0] = (_Float16)f0.x; v[1] = (_Float16)f0.y; v[2] = (_Float16)f0.z; v[3] = (_Float16)f0.w;
  v[4] = (_Float16)f1.x; v[5] = (_Float16)f1.y; v[6] = (_Float16)f1.z; v[7] = (_Float16)f1.w;
  *(half8*)(Xh + e) = v;
}

__global__ void lstm_pack_bias8(const float* __restrict__ bxi, const float* __restrict__ bhi,
                                const float* __restrict__ bxf, const float* __restrict__ bhf,
                                const float* __restrict__ bxg, const float* __restrict__ bhg,
                                const float* __restrict__ bxo, const float* __restrict__ bho,
                                float* __restrict__ bias) {
  int t = blockIdx.x * 256 + threadIdx.x;
  if (t >= 4096) return;
  const float* bx[4] = {bxi, bxf, bxg, bxo};
  const float* bh[4] = {bhi, bhf, bhg, bho};
  int q = t >> 4, r = t & 15;
  int g = q & 3, j = (q >> 2) * 16 + r;
  bias[t] = bx[g][j] + bh[g][j];
}

// ---------------- 4-deep-ring fused GEMM (BK=32) ----------------
__global__ __launch_bounds__(512, 2) void lstm_gemm_r9(
    const _Float16* __restrict__ Xh, const _Float16* __restrict__ Wt,
    const float* __restrict__ c, const float* __restrict__ bias,
    float* __restrict__ out) {
  __shared__ ushort sA[4][256 * 32];
  __shared__ ushort sB[4][256 * 32];

  int bid = blockIdx.x;                 // 512 blocks
  int xcd = bid & 7, idx = bid >> 3;    // idx 0..63
  int jt = xcd * 2 + (idx & 1);         // 0..15  (B panels L2-resident per XCD)
  int mt = idx >> 1;                    // 0..31
  int brow0 = mt * 256, bcol0 = jt * 256;

  int tid = threadIdx.x, lane = tid & 63, wave = tid >> 6;
  int wr = wave >> 2, wc = wave & 3;
  int l15 = lane & 15, l4 = lane >> 4;

  f32x4 acc[8][4] = {};                 // [m-frag 0..7][gate]

  // read-side swizzle: phys_slot = l4 ^ ((l15>>1)&3), lane-uniform across frags
  int roff = ((l4 ^ ((l15 >> 1) & 3)) << 3);
  int aoff0 = (wr * 128 + l15) * 32;
  int boff0 = (wc * 64 + l15) * 32;
  // stage-side source pre-permute (matching involution)
  int ssl = (((tid & 3) ^ ((tid >> 3) & 3)) << 3);
  int srow = tid >> 2;                  // 0..127 within an 8KB call

  auto stA = [&](int buf, int t, int a) {
    const _Float16* src = Xh + (size_t)(brow0 + a * 128 + srow) * 2048 + t * 32 + ssl;
    gload_lds16(src, &sA[buf][(a * 128 + wave * 16) * 32]);
  };
  auto stB = [&](int buf, int t, int a) {
    const _Float16* src = Wt + (size_t)(bcol0 + a * 128 + srow) * 2048 + t * 32 + ssl;
    gload_lds16(src, &sB[buf][(a * 128 + wave * 16) * 32]);
  };

#define STAGE(buf, t) do { stA(buf, t, 0); stA(buf, t, 1); \
                           stB(buf, t, 0); stB(buf, t, 1); } while (0)

#define STEP_COMPUTE(RB) do {                                                 \
    half8 af[8], bf[4];                                                       \
    _Pragma("unroll") for (int mi = 0; mi < 8; ++mi)                          \
      af[mi] = *(const half8*)&sA[RB][aoff0 + mi * 512 + roff];               \
    _Pragma("unroll") for (int nf = 0; nf < 4; ++nf)                          \
      bf[nf] = *(const half8*)&sB[RB][boff0 + nf * 512 + roff];               \
    LG0;                                                                      \
    __builtin_amdgcn_s_setprio(1);                                            \
    _Pragma("unroll") for (int mi = 0; mi < 8; ++mi)                          \
    _Pragma("unroll") for (int nf = 0; nf < 4; ++nf)                          \
      acc[mi][nf] = __builtin_amdgcn_mfma_f32_16x16x32_f16(af[mi], bf[nf],    \
                                                           acc[mi][nf], 0, 0, 0); \
    __builtin_amdgcn_s_setprio(0); } while (0)

  // Prologue: stage steps 0,1,2 into bufs 0,1,2; complete step0 (VMC leaves 8).
  STAGE(0, 0); STAGE(1, 1); STAGE(2, 2);
  VMC(8);
  BAR;

#pragma unroll 1
  for (int s = 0; s < 61; ++s) {
    int rb = s & 3, wb = (s + 3) & 3;
    STAGE(wb, s + 3);        // fully decoupled: wb's last reader was step s-2
    STEP_COMPUTE(rb);
    VMC(8);                  // completes stage(s-2) = step s+1's buffer
    BAR;
  }
  // s = 61 (buf 1): no stage; need stage(59)=step62 -> VMC(4)
  STEP_COMPUTE(1);
  VMC(4);
  BAR;
  // s = 62 (buf 2): need stage(60)=step63 -> VMC(0)
  STEP_COMPUTE(2);
  VMC(0);
  BAR;
  // s = 63 (buf 3)
  STEP_COMPUTE(3);

#undef STAGE
#undef STEP_COMPUTE

  // ---- fused LSTM epilogue (4 gates = 4 n-frags of this wave) ----
  int j = jt * 64 + wc * 16 + l15;
  int nbase = bcol0 + wc * 64 + l15;
  float bi  = bias[nbase + 0];
  float bff = bias[nbase + 16];
  float bg  = bias[nbase + 32];
  float bo  = bias[nbase + 48];
  float* hout = out;
  float* cout = out + (size_t)8192 * 1024;
  #pragma unroll
  for (int m = 0; m < 8; ++m) {
    #pragma unroll
    for (int r = 0; r < 4; ++r) {
      int grow = brow0 + wr * 128 + m * 16 + l4 * 4 + r;
      size_t o = (size_t)grow * 1024 + j;
      float zi = acc[m][0][r] + bi;
      float zf = acc[m][1][r] + bff;
      float zg = acc[m][2][r] + bg;
      float zo = acc[m][3][r] + bo;
      float ig = sigf(zi);
      float fg = sigf(zf);
      float gg = tanhf_(zg);
      float og = sigf(zo);
      float cold = c[o];
      float cn = fg * cold + ig * gg;
      hout[o] = og * tanhf_(cn);
      cout[o] = cn;
    }
  }
}

// ---------------- fallback path (round-1, validated) ----------------

__global__ void lstm_pack_w_v1(const float* __restrict__ Wxi, const float* __restrict__ Whi,
                               const float* __restrict__ Wxf, const float* __restrict__ Whf,
                               const float* __restrict__ Wxg, const float* __restrict__ Whg,
                               const float* __restrict__ Wxo, const float* __restrict__ Who,
                               _Float16* __restrict__ Wt) {
  __shared__ float tile[32][33];
  int nt = blockIdx.x;
  int kt = blockIdx.y;
  int g = nt & 3, jt = nt >> 2;
  const float* Wx[4] = {Wxi, Wxf, Wxg, Wxo};
  const float* Wh[4] = {Whi, Whf, Whg, Who};
  int k0 = kt * 32;
  const float* src = (k0 < 1024) ? (Wx[g] + (size_t)k0 * 1024)
                                 : (Wh[g] + (size_t)(k0 - 1024) * 1024);
  int j0 = jt * 32;
  int t = threadIdx.x;
  int cc = t & 31, r0 = t >> 5;
  #pragma unroll
  for (int p = 0; p < 4; ++p) {
    int r = p * 8 + r0;
    tile[r][cc] = src[(size_t)r * 1024 + j0 + cc];
  }
  __syncthreads();
  int jj = t >> 3, kk = (t & 7) * 4;
  half4 v;
  v[0] = (_Float16)tile[kk + 0][jj];
  v[1] = (_Float16)tile[kk + 1][jj];
  v[2] = (_Float16)tile[kk + 2][jj];
  v[3] = (_Float16)tile[kk + 3][jj];
  _Float16* dst = Wt + (size_t)(nt * 32 + jj) * 2048 + k0 + kk;
  *(half4*)dst = v;
}

__global__ void lstm_pack_bias_v1(const float* __restrict__ bxi, const float* __restrict__ bhi,
                                  const float* __restrict__ bxf, const float* __restrict__ bhf,
                                  const float* __restrict__ bxg, const float* __restrict__ bhg,
                                  const float* __restrict__ bxo, const float* __restrict__ bho,
                                  float* __restrict__ bias) {
  int t = blockIdx.x * 256 + threadIdx.x;
  if (t >= 4096) return;
  const float* bx[4] = {bxi, bxf, bxg, bxo};
  const float* bh[4] = {bhi, bhf, bhg, bho};
  int jt = t >> 7, g = (t >> 5) & 3, jj = t & 31;
  int j = jt * 32 + jj;
  bias[t] = bx[g][j] + bh[g][j];
}

__global__ __launch_bounds__(256, 2) void lstm_gemm_v1(
    const float* __restrict__ x, const float* __restrict__ h, const float* __restrict__ c,
    const _Float16* __restrict__ Wt, const float* __restrict__ bias,
    float* __restrict__ out) {
  __shared__ ushort sA[128 * 64];
  __shared__ ushort sB[128 * 64];
  int bid = blockIdx.x;
  int sbid = (bid & 7) * 256 + (bid >> 3);
  int mt = sbid >> 5, jt = sbid & 31;
  int brow0 = mt * 128;
  int tid = threadIdx.x;
  int lane = tid & 63, wave = tid >> 6;
  int wr = wave >> 1, wc = wave & 1;
  f32x4 acc[4][4] = {};
  int ar = tid >> 3;
  int as = tid & 7;
  int l3 = lane >> 3, l7w = lane & 7;
  int bsw = ((l7w ^ l3) << 3);
  int l15 = lane & 15, l4 = lane >> 4, l7 = lane & 7;
  for (int kt = 0; kt < 32; ++kt) {
    int k0 = kt * 64;
    const float* asrc = (k0 < 1024) ? (x + k0) : (h + (k0 - 1024));
    #pragma unroll
    for (int stp = 0; stp < 4; ++stp) {
      int row = stp * 32 + ar;
      const float* p = asrc + (size_t)(brow0 + row) * 1024 + as * 8;
      float4 f0 = *(const float4*)p;
      float4 f1 = *(const float4*)(p + 4);
      half8 hv;
      hv[0] = (_Float16)f0.x; hv[1] = (_Float16)f0.y;
      hv[2] = (_Float16)f0.z; hv[3] = (_Float16)f0.w;
      hv[4] = (_Float16)f1.x; hv[5] = (_Float16)f1.y;
      hv[6] = (_Float16)f1.z; hv[7] = (_Float16)f1.w;
      *(half8*)&sA[row * 64 + ((as ^ (row & 7)) << 3)] = hv;
    }
    #pragma unroll
    for (int ccall = 0; ccall < 4; ++ccall) {
      int rowbase = ccall * 32 + wave * 8;
      int grow = jt * 128 + rowbase + l3;
      const _Float16* src = Wt + (size_t)grow * 2048 + k0 + bsw;
      gload_lds16(src, &sB[rowbase * 64]);
    }
    __syncthreads();
    #pragma unroll
    for (int ks = 0; ks < 2; ++ks) {
      half8 af[4], bfr[4];
      #pragma unroll
      for (int mi = 0; mi < 4; ++mi) {
        int row = wr * 64 + mi * 16 + l15;
        af[mi] = *(const half8*)&sA[row * 64 + (((ks * 4 + l4) ^ l7) << 3)];
      }
      #pragma unroll
      for (int g = 0; g < 4; ++g) {
        int nr = g * 32 + wc * 16 + l15;
        bfr[g] = *(const half8*)&sB[nr * 64 + (((ks * 4 + l4) ^ l7) << 3)];
      }
      #pragma unroll
      for (int mi = 0; mi < 4; ++mi)
        #pragma unroll
        for (int g = 0; g < 4; ++g)
          acc[mi][g] = __builtin_amdgcn_mfma_f32_16x16x32_f16(af[mi], bfr[g], acc[mi][g], 0, 0, 0);
    }
    __syncthreads();
  }
  int j = jt * 32 + wc * 16 + l15;
  int nb = jt * 128 + wc * 16 + l15;
  float bi  = bias[nb + 0];
  float bff = bias[nb + 32];
  float bg  = bias[nb + 64];
  float bo  = bias[nb + 96];
  float* hout = out;
  float* cout = out + (size_t)8192 * 1024;
  #pragma unroll
  for (int mi = 0; mi < 4; ++mi) {
    #pragma unroll
    for (int r = 0; r < 4; ++r) {
      int grow = brow0 + wr * 64 + mi * 16 + l4 * 4 + r;
      size_t idx = (size_t)grow * 1024 + j;
      float zi = acc[mi][0][r] + bi;
      float zf = acc[mi][1][r] + bff;
      float zg = acc[mi][2][r] + bg;
      float zo = acc[mi][3][r] + bo;
      float ig = sigf(zi);
      float fg = sigf(zf);
      float gg = tanhf_(zg);
      float og = sigf(zo);
      float cold = c[idx];
      float cn = fg * cold + ig * gg;
      hout[idx] = og * tanhf_(cn);
      cout[idx] = cn;
    }
  }
}

extern "C" void kernel_launch(void* const* d_in, const int* in_sizes, int n_in,
                              void* d_out, int out_size, void* d_ws, size_t ws_size,
                              hipStream_t stream) {
  const float* x   = (const float*)d_in[0];
  const float* h   = (const float*)d_in[1];
  const float* c   = (const float*)d_in[2];
  const float* Wxi = (const float*)d_in[3];
  const float* Whi = (const float*)d_in[4];
  const float* bxi = (const float*)d_in[5];
  const float* bhi = (const float*)d_in[6];
  const float* Wxf = (const float*)d_in[7];
  const float* Whf = (const float*)d_in[8];
  const float* bxf = (const float*)d_in[9];
  const float* bhf = (const float*)d_in[10];
  const float* Wxg = (const float*)d_in[11];
  const float* Whg = (const float*)d_in[12];
  const float* bxg = (const float*)d_in[13];
  const float* bhg = (const float*)d_in[14];
  const float* Wxo = (const float*)d_in[15];
  const float* Who = (const float*)d_in[16];
  const float* bxo = (const float*)d_in[17];
  const float* bho = (const float*)d_in[18];
  float* out = (float*)d_out;

  const size_t WT_BYTES = (size_t)4096 * 2048 * 2;   // 16 MiB
  const size_t XH_BYTES = (size_t)8192 * 2048 * 2;   // 32 MiB
  const size_t NEED = WT_BYTES + XH_BYTES + 4096 * 4;

  if (ws_size >= NEED) {
    _Float16* Wt = (_Float16*)d_ws;
    _Float16* Xh = (_Float16*)((char*)d_ws + WT_BYTES);
    float* bias  = (float*)((char*)d_ws + WT_BYTES + XH_BYTES);
    lstm_pack_w8<<<dim3(128, 64), 256, 0, stream>>>(Wxi, Whi, Wxf, Whf, Wxg, Whg, Wxo, Who, Wt);
    lstm_pack_xh<<<8192, 256, 0, stream>>>(x, h, Xh);
    lstm_pack_bias8<<<16, 256, 0, stream>>>(bxi, bhi, bxf, bhf, bxg, bhg, bxo, bho, bias);
    lstm_gemm_r9<<<512, 512, 0, stream>>>(Xh, Wt, c, bias, out);
  } else {
    _Float16* Wt = (_Float16*)d_ws;
    float* bias  = (float*)((char*)d_ws + WT_BYTES);
    lstm_pack_w_v1<<<dim3(128, 64), 256, 0, stream>>>(Wxi, Whi, Wxf, Whf, Wxg, Whg, Wxo, Who, Wt);
    lstm_pack_bias_v1<<<16, 256, 0, stream>>>(bxi, bhi, bxf, bhf, bxg, bhg, bxo, bho, bias);
    lstm_gemm_v1<<<2048, 256, 0, stream>>>(x, h, c, Wt, bias, out);
  }
}